// Round 13
// baseline (315.543 us; speedup 1.0000x reference)
//
#include <hip/hip_runtime.h>

typedef short short8 __attribute__((ext_vector_type(8)));
typedef float f32x4 __attribute__((ext_vector_type(4)));

#define B_    64
#define CH_   8
#define NBC   512
#define MATE  65536      // ushorts per 256x256 plane
#define H_    251
#define PADX  73         // conv input tile LDS row stride (floats)
#define LDSW  40         // LDS row stride in ushort (80B): frag reads 2-way max

__device__ inline unsigned short bf16r(float f){
    unsigned u = __float_as_uint(f);
    u += 0x7fffu + ((u >> 16) & 1u);
    return (unsigned short)(u >> 16);
}
__device__ inline float bf16f(unsigned short h){ return __uint_as_float(((unsigned)h) << 16); }

// ---------------- conv: x[b] -> Yhi/Ylo ushort planes (row-major split bf16), zero-padded to 256.
// 4 channels per block; row loads hoisted across channels. ----------------
__global__ __launch_bounds__(256) void conv_pack(const float* __restrict__ x,
                                                 const float* __restrict__ w,
                                                 const float* __restrict__ bias,
                                                 unsigned short* __restrict__ Yhi,
                                                 unsigned short* __restrict__ Ylo,
                                                 int b_base) {
    __shared__ float xt[69 * PADX];
    __shared__ float wsm[148];                 // 4*36 weights + 4 bias

    int tid = threadIdx.x;
    int tile = blockIdx.x;                     // 0..15
    int lb = blockIdx.y;                       // local batch in chunk
    int cq = blockIdx.z;                       // channel quad 0..1
    int b = b_base + lb;
    int r0 = (tile >> 2) * 64, c0 = (tile & 3) * 64;

    if (tid < 144) wsm[tid] = w[cq * 144 + tid];
    if (tid < 4)   wsm[144 + tid] = bias[cq * 4 + tid];

    const float* xb = x + (size_t)b * 65536;
    for (int idx = tid; idx < 69 * PADX; idx += 256) {
        int row = idx / PADX, col = idx - row * PADX;
        float v = 0.f;
        if (col < 69) {
            int gr = r0 + row; if (gr > 255) gr = 255;
            int gc = c0 + col; if (gc > 255) gc = 255;
            v = xb[gr * 256 + gc];
        }
        xt[idx] = v;
    }
    __syncthreads();

    int tx = tid & 15, ty = tid >> 4;

    float acc[4][4][4];
    #pragma unroll
    for (int cc = 0; cc < 4; ++cc) {
        float bv = wsm[144 + cc];
        #pragma unroll
        for (int i = 0; i < 4; ++i)
            #pragma unroll
            for (int j = 0; j < 4; ++j) acc[cc][i][j] = bv;
    }

    #pragma unroll
    for (int ir = 0; ir < 9; ++ir) {
        float row[9];
        #pragma unroll
        for (int c = 0; c < 9; ++c) row[c] = xt[(ty * 4 + ir) * PADX + tx * 4 + c];
        #pragma unroll
        for (int cc = 0; cc < 4; ++cc) {
            const float* wc = &wsm[cc * 36];
            #pragma unroll
            for (int i = 0; i < 4; ++i) {
                int u = ir - i;
                if (u >= 0 && u < 6) {
                    #pragma unroll
                    for (int v = 0; v < 6; ++v) {
                        float wv = wc[u * 6 + v];
                        #pragma unroll
                        for (int j = 0; j < 4; ++j) acc[cc][i][j] += row[j + v] * wv;
                    }
                }
            }
        }
    }

    #pragma unroll
    for (int cc = 0; cc < 4; ++cc) {
        int ch = cq * 4 + cc;
        size_t mb = (size_t)(lb * 8 + ch) * MATE;
        #pragma unroll
        for (int i = 0; i < 4; ++i) {
            int gr = r0 + ty * 4 + i;
            unsigned short h4[4], l4[4];
            #pragma unroll
            for (int j = 0; j < 4; ++j) {
                int gc = c0 + tx * 4 + j;
                float v = (gr < H_ && gc < H_) ? acc[cc][i][j] : 0.f;
                unsigned short h = bf16r(v);
                h4[j] = h;
                l4[j] = bf16r(v - bf16f(h));
            }
            size_t off = mb + (size_t)gr * 256 + c0 + tx * 4;
            *(ushort4*)(Yhi + off) = make_ushort4(h4[0], h4[1], h4[2], h4[3]);
            *(ushort4*)(Ylo + off) = make_ushort4(l4[0], l4[1], l4[2], l4[3]);
        }
    }
}

// ---------------- MFMA GEMM (split bf16, 3 chains) on ushort hi/lo planes.
// PHASE1: out = Y*Y. A linear-staged from Y rows; B transpose-staged from Y cols.
//         Writes MT hi/lo (MT[c][r] = M[r][c], contiguous). pdiag=t2, pfull=t3=sum M_ij*Y_ji.
// PHASE2: out = M*M. A transpose-staged from MT cols; B linear-staged from MT rows.
//         No writes. pdiag=t4, pfull=t5=sum P_ij*Y_ji.
template<int PHASE>
__global__ __launch_bounds__(256) void gemm_mfma(const unsigned short* __restrict__ Xhi,
                                                 const unsigned short* __restrict__ Xlo,
                                                 const unsigned short* __restrict__ Yehi,
                                                 const unsigned short* __restrict__ Yelo,
                                                 unsigned short* __restrict__ MTohi,
                                                 unsigned short* __restrict__ MTolo,
                                                 double* __restrict__ pdiag,
                                                 double* __restrict__ pfull,
                                                 int bc_base, int cur) {
    __shared__ __align__(16) unsigned short Ahi[128 * LDSW];
    __shared__ __align__(16) unsigned short Alo[128 * LDSW];
    __shared__ __align__(16) unsigned short Bhi[128 * LDSW];
    __shared__ __align__(16) unsigned short Blo[128 * LDSW];
    __shared__ double redbuf[8];

    int tid = threadIdx.x;

    // XCD-colocating bijective remap (cur always a multiple of 8)
    int hw = blockIdx.x;
    int xcd = hw & 7, s = hw >> 3;
    int mpx = cur >> 3;
    int lbc = xcd * mpx + (s >> 2);
    int t4 = s & 3;
    int by = t4 >> 1, bx = t4 & 1;
    int bi = by * 128, bj = bx * 128;
    int bc = bc_base + lbc;

    const unsigned short* Xh = Xhi + (size_t)lbc * MATE;
    const unsigned short* Xl = Xlo + (size_t)lbc * MATE;

    int wid = tid >> 6, l = tid & 63;
    int wr = wid >> 1, wc = wid & 1;
    int l15 = l & 15, lk = l >> 4;

    f32x4 acc[4][4];
    #pragma unroll
    for (int m = 0; m < 4; ++m)
        #pragma unroll
        for (int n = 0; n < 4; ++n) acc[m][n] = (f32x4){0.f, 0.f, 0.f, 0.f};

    // linear-stage mapping: 512 (row,chunk) pairs, 2 per thread
    // transpose-stage mapping: thread owns col-pair cp (local cols 2cp,2cp+1), k-chunk kc
    const int cp = tid & 63;
    const int kc = tid >> 6;

    const int linbase = (PHASE == 1) ? bi : bj;   // linear stage target rows
    const int trbase  = (PHASE == 1) ? bj : bi;   // transpose stage source cols
    unsigned short* LinHi = (PHASE == 1) ? Ahi : Bhi;
    unsigned short* LinLo = (PHASE == 1) ? Alo : Blo;
    unsigned short* TrHi  = (PHASE == 1) ? Bhi : Ahi;
    unsigned short* TrLo  = (PHASE == 1) ? Blo : Alo;

    for (int k0 = 0; k0 < 256; k0 += 32) {
        // ---- linear stage: L[r][k] = X[linbase+r][k0+k]  (pure copy) ----
        #pragma unroll
        for (int p = 0; p < 2; ++p) {
            int idx = p * 256 + tid;
            int row = idx >> 2, ch = idx & 3;
            size_t off = (size_t)(linbase + row) * 256 + k0 + ch * 8;
            *(uint4*)&LinHi[row * LDSW + ch * 8] = *(const uint4*)(Xh + off);
            *(uint4*)&LinLo[row * LDSW + ch * 8] = *(const uint4*)(Xl + off);
        }
        // ---- transpose stage: T[c][k] = X[k0+k][trbase+c]  (uint pair-merge) ----
        {
            const unsigned short* sh = Xh + (size_t)(k0 + kc * 8) * 256 + trbase + 2 * cp;
            const unsigned short* sl = Xl + (size_t)(k0 + kc * 8) * 256 + trbase + 2 * cp;
            unsigned uh[8], ul[8];
            #pragma unroll
            for (int kk = 0; kk < 8; ++kk) {
                uh[kk] = *(const unsigned*)(sh + kk * 256);
                ul[kk] = *(const unsigned*)(sl + kk * 256);
            }
            unsigned e[4], o[4], el[4], ol[4];
            #pragma unroll
            for (int q = 0; q < 4; ++q) {
                e[q]  = (uh[2*q] & 0xffffu) | (uh[2*q+1] << 16);
                o[q]  = (uh[2*q] >> 16)     | (uh[2*q+1] & 0xffff0000u);
                el[q] = (ul[2*q] & 0xffffu) | (ul[2*q+1] << 16);
                ol[q] = (ul[2*q] >> 16)     | (ul[2*q+1] & 0xffff0000u);
            }
            *(uint4*)&TrHi[(2*cp)     * LDSW + kc * 8] = make_uint4(e[0], e[1], e[2], e[3]);
            *(uint4*)&TrHi[(2*cp + 1) * LDSW + kc * 8] = make_uint4(o[0], o[1], o[2], o[3]);
            *(uint4*)&TrLo[(2*cp)     * LDSW + kc * 8] = make_uint4(el[0], el[1], el[2], el[3]);
            *(uint4*)&TrLo[(2*cp + 1) * LDSW + kc * 8] = make_uint4(ol[0], ol[1], ol[2], ol[3]);
        }
        __syncthreads();

        short8 ah[4], al[4], bh[4], bl[4];
        #pragma unroll
        for (int m = 0; m < 4; ++m) {
            int r = wr * 64 + m * 16 + l15;
            ah[m] = *(const short8*)&Ahi[r * LDSW + lk * 8];
            al[m] = *(const short8*)&Alo[r * LDSW + lk * 8];
        }
        #pragma unroll
        for (int n = 0; n < 4; ++n) {
            int c = wc * 64 + n * 16 + l15;
            bh[n] = *(const short8*)&Bhi[c * LDSW + lk * 8];
            bl[n] = *(const short8*)&Blo[c * LDSW + lk * 8];
        }
        #pragma unroll
        for (int m = 0; m < 4; ++m)
            #pragma unroll
            for (int n = 0; n < 4; ++n) {
                acc[m][n] = __builtin_amdgcn_mfma_f32_16x16x32_bf16(ah[m], bh[n], acc[m][n], 0, 0, 0);
                acc[m][n] = __builtin_amdgcn_mfma_f32_16x16x32_bf16(ah[m], bl[n], acc[m][n], 0, 0, 0);
                acc[m][n] = __builtin_amdgcn_mfma_f32_16x16x32_bf16(al[m], bh[n], acc[m][n], 0, 0, 0);
            }
        __syncthreads();
    }

    // ---- epilogue: partial traces (+ MT write in PHASE1); Y_ji = Ye[cg][rg0..3] contiguous ----
    const unsigned short* Yh = Yehi + (size_t)lbc * MATE;
    const unsigned short* Yl = Yelo + (size_t)lbc * MATE;
    float s_full = 0.f, s_diag = 0.f;
    #pragma unroll
    for (int m = 0; m < 4; ++m) {
        int rg0 = bi + wr * 64 + m * 16 + lk * 4;
        #pragma unroll
        for (int n = 0; n < 4; ++n) {
            int cg = bj + wc * 64 + n * 16 + l15;
            size_t yoff = (size_t)cg * 256 + rg0;
            ushort4 yh = *(const ushort4*)(Yh + yoff);
            ushort4 yl = *(const ushort4*)(Yl + yoff);
            unsigned short yhv[4] = {yh.x, yh.y, yh.z, yh.w};
            unsigned short ylv[4] = {yl.x, yl.y, yl.z, yl.w};
            f32x4 v = acc[m][n];
            unsigned short mh[4], ml[4];
            #pragma unroll
            for (int reg = 0; reg < 4; ++reg) {
                float val = v[reg];
                s_full += val * (bf16f(yhv[reg]) + bf16f(ylv[reg]));
                if (rg0 + reg == cg) s_diag += val;
                if (PHASE == 1) {
                    unsigned short h = bf16r(val);
                    mh[reg] = h;
                    ml[reg] = bf16r(val - bf16f(h));
                }
            }
            if (PHASE == 1) {
                size_t moff = (size_t)lbc * MATE + (size_t)cg * 256 + rg0;
                *(ushort4*)(MTohi + moff) = make_ushort4(mh[0], mh[1], mh[2], mh[3]);
                *(ushort4*)(MTolo + moff) = make_ushort4(ml[0], ml[1], ml[2], ml[3]);
            }
        }
    }

    // reduce partials
    double df = (double)s_full, dd = (double)s_diag;
    #pragma unroll
    for (int off = 32; off > 0; off >>= 1) {
        df += __shfl_down(df, off, 64);
        dd += __shfl_down(dd, off, 64);
    }
    __syncthreads();
    if (l == 0) { redbuf[wid] = df; redbuf[4 + wid] = dd; }
    __syncthreads();
    if (tid == 0) {
        pfull[(size_t)bc * 4 + by * 2 + bx] =
            redbuf[0] + redbuf[1] + redbuf[2] + redbuf[3];
        if (bx == by)
            pdiag[(size_t)bc * 2 + bx] =
                redbuf[4] + redbuf[5] + redbuf[6] + redbuf[7];
    }
}

// ---------------- combine ----------------
__global__ void combine(const double* __restrict__ p2, const double* __restrict__ p3,
                        const double* __restrict__ p4, const double* __restrict__ p5,
                        const float* __restrict__ coef, float* __restrict__ out) {
    int b = threadIdx.x;
    if (b >= B_) return;
    const double numel = (double)(H_ * H_);
    double acc = 0.0;
    for (int ch = 0; ch < CH_; ++ch) {
        int bc = b * CH_ + ch;
        double t[4];
        t[0] = p2[bc * 2] + p2[bc * 2 + 1];
        t[1] = p3[bc * 4] + p3[bc * 4 + 1] + p3[bc * 4 + 2] + p3[bc * 4 + 3];
        t[2] = p4[bc * 2] + p4[bc * 2 + 1];
        t[3] = p5[bc * 4] + p5[bc * 4 + 1] + p5[bc * 4 + 2] + p5[bc * 4 + 3];
        double npow_i = numel;
        for (int i = 0; i < 4; ++i) {
            double tv = t[i];
            double p = tv, d = npow_i;
            for (int j = 0; j < 3; ++j) {
                acc += (double)coef[ch * 12 + i * 3 + j] * (p / d);
                p *= tv;
                d *= numel;
            }
            npow_i *= numel;
        }
    }
    out[b] = (float)acc;
}

extern "C" void kernel_launch(void* const* d_in, const int* in_sizes, int n_in,
                              void* d_out, int out_size, void* d_ws, size_t ws_size,
                              hipStream_t stream) {
    const float* x    = (const float*)d_in[0];
    const float* w    = (const float*)d_in[1];
    const float* bias = (const float*)d_in[2];
    const float* coef = (const float*)d_in[3];
    float* out = (float*)d_out;

    // head: p2[512*2] p3[512*4] p4[512*2] p5[512*4] doubles (48KB) in first 64KB
    double* p2 = (double*)d_ws;
    double* p3 = p2 + NBC * 2;
    double* p4 = p3 + NBC * 4;
    double* p5 = p4 + NBC * 2;
    const size_t head = 65536;

    const size_t per_plane = (size_t)MATE * 2;               // 128 KB per ushort plane
    size_t avail = (ws_size > head) ? ws_size - head : 0;
    int NC = (int)(avail / (4 * per_plane));                 // Yhi,Ylo,MThi,MTlo = 512 KB/matrix
    NC &= ~7;                                                // whole batches of 8 channels
    if (NC > 256) NC = 256;                                  // chunk WS <= 128MB (proven-safe)
    if (NC < 8) NC = 8;

    unsigned short* Yhi  = (unsigned short*)((char*)d_ws + head);
    unsigned short* Ylo  = Yhi  + (size_t)NC * MATE;
    unsigned short* MThi = Ylo  + (size_t)NC * MATE;
    unsigned short* MTlo = MThi + (size_t)NC * MATE;

    for (int bc0 = 0; bc0 < NBC; bc0 += NC) {
        int cur = NBC - bc0;
        if (cur > NC) cur = NC;
        int nb = cur / 8;
        conv_pack<<<dim3(16, nb, 2), 256, 0, stream>>>(x, w, bias, Yhi, Ylo, bc0 / 8);
        // G1: M = Y*Y ; t2 = tr(M), t3 = sum M_ij * Y_ji ; writes MT planes
        gemm_mfma<1><<<cur * 4, 256, 0, stream>>>(Yhi, Ylo, Yhi, Ylo, MThi, MTlo, p2, p3, bc0, cur);
        // G2: P = M*M ; t4 = tr(P), t5 = sum P_ij * Y_ji
        gemm_mfma<2><<<cur * 4, 256, 0, stream>>>(MThi, MTlo, Yhi, Ylo, nullptr, nullptr, p4, p5, bc0, cur);
    }
    combine<<<1, 64, 0, stream>>>(p2, p3, p4, p5, coef, out);
}

// Round 14
// 242.020 us; speedup vs baseline: 1.3038x; 1.3038x over previous
//
#include <hip/hip_runtime.h>

typedef short short8 __attribute__((ext_vector_type(8)));
typedef float f32x4 __attribute__((ext_vector_type(4)));

#define B_    64
#define CH_   8
#define NBC   512
#define MATU  65536      // elements per padded 256x256 matrix
#define H_    251
#define PADX  73         // conv input tile LDS row stride (floats)
#define LDSW  40         // A-plane LDS row stride in ushort (80B): frag reads 2-way max

__device__ inline unsigned short bf16r(float f){
    unsigned u = __float_as_uint(f);
    u += 0x7fffu + ((u >> 16) & 1u);
    return (unsigned short)(u >> 16);
}
__device__ inline float bf16f(unsigned short h){ return __uint_as_float(((unsigned)h) << 16); }
__device__ inline unsigned packsplit(float v){
    unsigned short h = bf16r(v);
    unsigned short l = bf16r(v - bf16f(h));
    return (((unsigned)h) << 16) | (unsigned)l;
}
__device__ inline float unpackf(unsigned u){
    return __uint_as_float(u & 0xffff0000u) + bf16f((unsigned short)(u & 0xffffu));
}

// ---------------- conv: x[b] -> Ypk (packed hi|lo u32, row-major), zero-padded to 256.
// 4 channels per block (blockIdx.z = channel quad); row loads hoisted across channels. ----------------
__global__ __launch_bounds__(256) void conv_pack(const float* __restrict__ x,
                                                 const float* __restrict__ w,
                                                 const float* __restrict__ bias,
                                                 unsigned* __restrict__ Ypk,
                                                 int b_base) {
    __shared__ float xt[69 * PADX];
    __shared__ float wsm[148];                 // 4*36 weights + 4 bias

    int tid = threadIdx.x;
    int tile = blockIdx.x;                     // 0..15
    int lb = blockIdx.y;                       // local batch in chunk
    int cq = blockIdx.z;                       // channel quad 0..1
    int b = b_base + lb;
    int r0 = (tile >> 2) * 64, c0 = (tile & 3) * 64;

    if (tid < 144) wsm[tid] = w[cq * 144 + tid];
    if (tid < 4)   wsm[144 + tid] = bias[cq * 4 + tid];

    const float* xb = x + (size_t)b * 65536;
    for (int idx = tid; idx < 69 * PADX; idx += 256) {
        int row = idx / PADX, col = idx - row * PADX;
        float v = 0.f;
        if (col < 69) {
            int gr = r0 + row; if (gr > 255) gr = 255;
            int gc = c0 + col; if (gc > 255) gc = 255;
            v = xb[gr * 256 + gc];
        }
        xt[idx] = v;
    }
    __syncthreads();

    int tx = tid & 15, ty = tid >> 4;

    float acc[4][4][4];
    #pragma unroll
    for (int cc = 0; cc < 4; ++cc) {
        float bv = wsm[144 + cc];
        #pragma unroll
        for (int i = 0; i < 4; ++i)
            #pragma unroll
            for (int j = 0; j < 4; ++j) acc[cc][i][j] = bv;
    }

    #pragma unroll
    for (int ir = 0; ir < 9; ++ir) {
        float row[9];
        #pragma unroll
        for (int c = 0; c < 9; ++c) row[c] = xt[(ty * 4 + ir) * PADX + tx * 4 + c];
        #pragma unroll
        for (int cc = 0; cc < 4; ++cc) {
            const float* wc = &wsm[cc * 36];
            #pragma unroll
            for (int i = 0; i < 4; ++i) {
                int u = ir - i;
                if (u >= 0 && u < 6) {
                    #pragma unroll
                    for (int v = 0; v < 6; ++v) {
                        float wv = wc[u * 6 + v];
                        #pragma unroll
                        for (int j = 0; j < 4; ++j) acc[cc][i][j] += row[j + v] * wv;
                    }
                }
            }
        }
    }

    #pragma unroll
    for (int cc = 0; cc < 4; ++cc) {
        int ch = cq * 4 + cc;
        unsigned pk[4][4];
        #pragma unroll
        for (int i = 0; i < 4; ++i) {
            int gr = r0 + ty * 4 + i;
            #pragma unroll
            for (int j = 0; j < 4; ++j) {
                int gc = c0 + tx * 4 + j;
                float v = (gr < H_ && gc < H_) ? acc[cc][i][j] : 0.f;
                pk[i][j] = packsplit(v);
            }
        }
        unsigned* yrow = Ypk + (size_t)(lb * 8 + ch) * MATU;
        #pragma unroll
        for (int i = 0; i < 4; ++i) {
            uint4 v = make_uint4(pk[i][0], pk[i][1], pk[i][2], pk[i][3]);
            *(uint4*)&yrow[(size_t)(r0 + ty * 4 + i) * 256 + c0 + tx * 4] = v;
        }
    }
}

// ---------------- MFMA GEMM out = X*X (split bf16, 3 chains), X = Apk (row-major packed).
// A staged in [128][LDSW] planes; B transpose-staged into subtiled [kb:4][col:128][8] planes
// (dword global loads, 2-way-max LDS writes, sequential b128 frag reads).
// LDS right-sized to 36864B (was 53248 with 8KB/plane dead space) -> 4 blocks/CU.
// PHASE1 (X=Y): writes M row-major; pdiag=t2=tr(M), pfull=t3=sum M_ij*Y_ji
// PHASE2 (X=M): no writes;          pdiag=t4,       pfull=t5=sum (M*M)_ij*Y_ji
template<int PHASE>
__global__ __launch_bounds__(256, 4) void gemm_mfma(const unsigned* __restrict__ Apk,
                                                    const unsigned* __restrict__ Ypk,
                                                    unsigned* __restrict__ Mpk,
                                                    double* __restrict__ pdiag,
                                                    double* __restrict__ pfull,
                                                    int bc_base, int cur) {
    __shared__ __align__(16) char smem[36864];   // Ahi[128][40]us | Alo[128][40]us | Bhi[4][128][8]us | Blo[4][128][8]us
    __shared__ double redbuf[8];

    unsigned short* Ahi = (unsigned short*)smem;
    unsigned short* Alo = (unsigned short*)(smem + 10240);
    unsigned short* Bhi = (unsigned short*)(smem + 20480);
    unsigned short* Blo = (unsigned short*)(smem + 28672);

    int tid = threadIdx.x;

    // XCD-colocating bijective remap (cur always a multiple of 8)
    int hw = blockIdx.x;
    int xcd = hw & 7, s = hw >> 3;
    int mpx = cur >> 3;
    int lbc = xcd * mpx + (s >> 2);
    int t4 = s & 3;
    int by = t4 >> 1, bx = t4 & 1;
    int bi = by * 128, bj = bx * 128;
    int bc = bc_base + lbc;

    const unsigned* A = Apk + (size_t)lbc * MATU;

    int wid = tid >> 6, l = tid & 63;
    int wr = wid >> 1, wc = wid & 1;
    int l15 = l & 15, lk = l >> 4;

    f32x4 acc[4][4];
    #pragma unroll
    for (int m = 0; m < 4; ++m)
        #pragma unroll
        for (int n = 0; n < 4; ++n) acc[m][n] = (f32x4){0.f, 0.f, 0.f, 0.f};

    // B-stage mapping: lane owns cols cl+32j (j=0..3), ks kq..kq+3
    const int cl  = tid & 31;
    const int grp = tid >> 5;            // 0..7
    const int kq  = grp * 4;             // 0,4,...,28
    const int kb  = grp >> 1;            // k-block 0..3
    const int koff = (grp & 1) * 4;      // offset within 8-k block

    for (int k0 = 0; k0 < 256; k0 += 32) {
        // ---- A stage: rows bi..bi+127, k0..k0+31, unpack u32 -> hi/lo planes ----
        #pragma unroll
        for (int p = 0; p < 4; ++p) {
            int g = p * 256 + tid;
            int row = g >> 3, chn = g & 7;
            uint4 qa = *(const uint4*)(A + (size_t)(bi + row) * 256 + k0 + chn * 4);
            *(ushort4*)&Ahi[row * LDSW + chn * 4] =
                make_ushort4(qa.x >> 16, qa.y >> 16, qa.z >> 16, qa.w >> 16);
            *(ushort4*)&Alo[row * LDSW + chn * 4] =
                make_ushort4(qa.x & 0xffff, qa.y & 0xffff, qa.z & 0xffff, qa.w & 0xffff);
        }
        // ---- B stage (transpose to subtiled [kb][col][8]): dword loads, floor-rate LDS writes ----
        {
            const unsigned* Bp = A + (size_t)(k0 + kq) * 256 + bj + cl;
            unsigned d[4][4];
            #pragma unroll
            for (int i = 0; i < 4; ++i)
                #pragma unroll
                for (int j = 0; j < 4; ++j)
                    d[i][j] = Bp[i * 256 + j * 32];
            #pragma unroll
            for (int j = 0; j < 4; ++j) {
                int c = cl + 32 * j;
                *(ushort4*)&Bhi[kb * 1024 + c * 8 + koff] =
                    make_ushort4(d[0][j] >> 16, d[1][j] >> 16, d[2][j] >> 16, d[3][j] >> 16);
                *(ushort4*)&Blo[kb * 1024 + c * 8 + koff] =
                    make_ushort4(d[0][j] & 0xffff, d[1][j] & 0xffff, d[2][j] & 0xffff, d[3][j] & 0xffff);
            }
        }
        __syncthreads();

        short8 ah[4], al[4], bh[4], bl[4];
        #pragma unroll
        for (int m = 0; m < 4; ++m) {
            int r = wr * 64 + m * 16 + l15;
            ah[m] = *(const short8*)&Ahi[r * LDSW + lk * 8];
            al[m] = *(const short8*)&Alo[r * LDSW + lk * 8];
        }
        #pragma unroll
        for (int n = 0; n < 4; ++n) {
            int c = wc * 64 + n * 16 + l15;
            bh[n] = *(const short8*)&Bhi[lk * 1024 + c * 8];
            bl[n] = *(const short8*)&Blo[lk * 1024 + c * 8];
        }
        #pragma unroll
        for (int m = 0; m < 4; ++m)
            #pragma unroll
            for (int n = 0; n < 4; ++n) {
                acc[m][n] = __builtin_amdgcn_mfma_f32_16x16x32_bf16(ah[m], bh[n], acc[m][n], 0, 0, 0);
                acc[m][n] = __builtin_amdgcn_mfma_f32_16x16x32_bf16(ah[m], bl[n], acc[m][n], 0, 0, 0);
                acc[m][n] = __builtin_amdgcn_mfma_f32_16x16x32_bf16(al[m], bh[n], acc[m][n], 0, 0, 0);
            }
        __syncthreads();
    }

    // ---- epilogue: partial traces (+ M write in PHASE1); Y_ji read from row-major Y (contiguous 16B) ----
    const unsigned* Yb = Ypk + (size_t)lbc * MATU;
    unsigned* Mw = (PHASE == 1) ? (Mpk + (size_t)lbc * MATU) : nullptr;
    float s_full = 0.f, s_diag = 0.f;
    #pragma unroll
    for (int m = 0; m < 4; ++m) {
        int rg0 = bi + wr * 64 + m * 16 + lk * 4;
        #pragma unroll
        for (int n = 0; n < 4; ++n) {
            int cg = bj + wc * 64 + n * 16 + l15;
            uint4 yq = *(const uint4*)(Yb + (size_t)cg * 256 + rg0);   // Y[cg][rg0..rg0+3]
            unsigned yu[4] = {yq.x, yq.y, yq.z, yq.w};
            f32x4 v = acc[m][n];
            #pragma unroll
            for (int reg = 0; reg < 4; ++reg) {
                float val = v[reg];
                s_full += val * unpackf(yu[reg]);
                if (rg0 + reg == cg) s_diag += val;
                if (PHASE == 1) Mw[(size_t)(rg0 + reg) * 256 + cg] = packsplit(val);
            }
        }
    }

    // reduce partials
    double df = (double)s_full, dd = (double)s_diag;
    #pragma unroll
    for (int off = 32; off > 0; off >>= 1) {
        df += __shfl_down(df, off, 64);
        dd += __shfl_down(dd, off, 64);
    }
    __syncthreads();
    if (l == 0) { redbuf[wid] = df; redbuf[4 + wid] = dd; }
    __syncthreads();
    if (tid == 0) {
        pfull[(size_t)bc * 4 + by * 2 + bx] =
            redbuf[0] + redbuf[1] + redbuf[2] + redbuf[3];
        if (bx == by)
            pdiag[(size_t)bc * 2 + bx] =
                redbuf[4] + redbuf[5] + redbuf[6] + redbuf[7];
    }
}

// ---------------- combine ----------------
__global__ void combine(const double* __restrict__ p2, const double* __restrict__ p3,
                        const double* __restrict__ p4, const double* __restrict__ p5,
                        const float* __restrict__ coef, float* __restrict__ out) {
    int b = threadIdx.x;
    if (b >= B_) return;
    const double numel = (double)(H_ * H_);
    double acc = 0.0;
    for (int ch = 0; ch < CH_; ++ch) {
        int bc = b * CH_ + ch;
        double t[4];
        t[0] = p2[bc * 2] + p2[bc * 2 + 1];
        t[1] = p3[bc * 4] + p3[bc * 4 + 1] + p3[bc * 4 + 2] + p3[bc * 4 + 3];
        t[2] = p4[bc * 2] + p4[bc * 2 + 1];
        t[3] = p5[bc * 4] + p5[bc * 4 + 1] + p5[bc * 4 + 2] + p5[bc * 4 + 3];
        double npow_i = numel;
        for (int i = 0; i < 4; ++i) {
            double tv = t[i];
            double p = tv, d = npow_i;
            for (int j = 0; j < 3; ++j) {
                acc += (double)coef[ch * 12 + i * 3 + j] * (p / d);
                p *= tv;
                d *= numel;
            }
            npow_i *= numel;
        }
    }
    out[b] = (float)acc;
}

extern "C" void kernel_launch(void* const* d_in, const int* in_sizes, int n_in,
                              void* d_out, int out_size, void* d_ws, size_t ws_size,
                              hipStream_t stream) {
    const float* x    = (const float*)d_in[0];
    const float* w    = (const float*)d_in[1];
    const float* bias = (const float*)d_in[2];
    const float* coef = (const float*)d_in[3];
    float* out = (float*)d_out;

    // head: p2[512*2] p3[512*4] p4[512*2] p5[512*4] doubles (48KB) in first 64KB
    double* p2 = (double*)d_ws;
    double* p3 = p2 + NBC * 2;
    double* p4 = p3 + NBC * 4;
    double* p5 = p4 + NBC * 2;
    const size_t head = 65536;

    const size_t per_mat = (size_t)MATU * 4;                 // 256 KB per packed matrix plane
    size_t avail = (ws_size > head) ? ws_size - head : 0;
    int NC = (int)(avail / (2 * per_mat));                   // Y + M per matrix (512 KB)
    NC &= ~7;                                                // whole batches of 8 channels
    if (NC > 256) NC = 256;                                  // chunk WS <= 128MB (proven-safe)
    if (NC < 8) NC = 8;

    unsigned* Ypk = (unsigned*)((char*)d_ws + head);
    unsigned* Mpk = Ypk + (size_t)NC * MATU;

    for (int bc0 = 0; bc0 < NBC; bc0 += NC) {
        int cur = NBC - bc0;
        if (cur > NC) cur = NC;
        int nb = cur / 8;
        conv_pack<<<dim3(16, nb, 2), 256, 0, stream>>>(x, w, bias, Ypk, bc0 / 8);
        // G1: M = Y*Y ; t2 = tr(M), t3 = sum M_ij * Y_ji
        gemm_mfma<1><<<cur * 4, 256, 0, stream>>>(Ypk, Ypk, Mpk, p2, p3, bc0, cur);
        // G2: P = M*M ; t4 = tr(P), t5 = sum P_ij * Y_ji
        gemm_mfma<2><<<cur * 4, 256, 0, stream>>>(Mpk, Ypk, nullptr, p4, p5, bc0, cur);
    }
    combine<<<1, 64, 0, stream>>>(p2, p3, p4, p5, coef, out);
}